// Round 8
// baseline (2386.022 us; speedup 1.0000x reference)
//
#include <hip/hip_runtime.h>

typedef _Float16 f16;
typedef __attribute__((ext_vector_type(4))) _Float16 f16x4;
typedef __attribute__((ext_vector_type(8))) _Float16 f16x8;
typedef __attribute__((ext_vector_type(16))) float f32x16;

#define MT 64            // batch rows per block
#define NBF 2            // batch fragments (MT/32)
#define LDSP 1024        // LDS row pitch bytes (512 f16 features)

// Packed-weight fragment offsets (f16 elements) inside d_ws
#define OFF2 0
#define OFF3 32768
#define OFF4 163840
#define OFF5 425984
#define OFF6 688128
#define OFF7 950272
#define OFF8 1081344
#define OFF9 1114112
#define TOTAL_FRAG_LANES 139776

// 32 rows -> 32 distinct 16B slots: conflict-free-ish b128 column reads.
__device__ __forceinline__ uint32_t swz(int row, int colbytes) {
  return (uint32_t)(row * LDSP + (colbytes ^ ((row & 31) << 4)));
}

// weight repack: fp32 [K][N] -> fp16 A-fragment order.
// frag f = kf*MF + mf ; lane l holds m = mf*32 + (l&31), k = kf*16 + (l>>5)*8 + i
__global__ void repack_kernel(const float* __restrict__ W2, const float* __restrict__ W3,
                              const float* __restrict__ W4, const float* __restrict__ W5,
                              const float* __restrict__ W6, const float* __restrict__ W7,
                              const float* __restrict__ W8, const float* __restrict__ W9,
                              f16* __restrict__ ws) {
  int gid = blockIdx.x * 256 + threadIdx.x;
  if (gid >= TOTAL_FRAG_LANES) return;
  const float* src; int N, NT; size_t dst; int local;
  if      (gid <   4096) { src = W2; N = 256; NT = 8;  dst = OFF2; local = gid;          }
  else if (gid <  20480) { src = W3; N = 512; NT = 16; dst = OFF3; local = gid -   4096; }
  else if (gid <  53248) { src = W4; N = 512; NT = 16; dst = OFF4; local = gid -  20480; }
  else if (gid <  86016) { src = W5; N = 512; NT = 16; dst = OFF5; local = gid -  53248; }
  else if (gid < 118784) { src = W6; N = 512; NT = 16; dst = OFF6; local = gid -  86016; }
  else if (gid < 135168) { src = W7; N = 256; NT = 8;  dst = OFF7; local = gid - 118784; }
  else if (gid < 139264) { src = W8; N = 128; NT = 4;  dst = OFF8; local = gid - 135168; }
  else                   { src = W9; N = 3;   NT = 1;  dst = OFF9; local = gid - 139264; }
  int lane = local & 63;
  int frag = local >> 6;
  int kf = frag / NT, nf = frag % NT;
  int n  = nf * 32 + (lane & 31);
  int kb = kf * 16 + ((lane >> 5) << 3);
  f16x8 v;
  #pragma unroll
  for (int i = 0; i < 8; ++i) {
    float val = (n < N) ? src[(size_t)(kb + i) * N + n] : 0.0f;
    v[i] = (f16)val;
  }
  *reinterpret_cast<f16x8*>(ws + dst + (size_t)local * 8) = v;
}

// One layer: D = W_frag(A) x act(B).  act is [batch][feature] f16 in LDS.
// THIN-TILE / MAX-TLP: FM = MF/WMG kept at 1 on wide layers; 16 waves, each
// wave owns one out-feature fragment column -> 1 weight load + 2 ds_reads +
// 2 MFMAs per kf.  8 waves/SIMD hide L2/LDS latency by interleave.
// Waves with wid >= WMG*WBG idle through to the barrier (small layers).
template<int KT, int MF, int WMG, int WBG>
__device__ __forceinline__ void run_layer(char* act, const f16* __restrict__ wp,
                                          const float* __restrict__ bias) {
  constexpr int FM  = MF / WMG;    // out-feature frags per wave
  constexpr int FB  = NBF / WBG;   // batch frags per wave
  const int tid   = threadIdx.x;
  const int lane  = tid & 63;
  const int wid   = tid >> 6;
  const int wm    = wid / WBG;
  const int wb    = wid % WBG;
  const int mlane = lane & 31;
  const int h     = lane >> 5;

  if (wid < WMG * WBG) {
    f32x16 acc[FM][FB];
    #pragma unroll
    for (int fm = 0; fm < FM; ++fm) {
      const int mbase = (wm * FM + fm) * 32;
      #pragma unroll
      for (int g = 0; g < 4; ++g) {
        const float4 bb = *reinterpret_cast<const float4*>(&bias[mbase + g * 8 + 4 * h]);
        #pragma unroll
        for (int j = 0; j < 4; ++j)
          #pragma unroll
          for (int fb = 0; fb < FB; ++fb)
            acc[fm][fb][g * 4 + j] = ((const float*)&bb)[j];
      }
    }

    const f16x8* __restrict__ wfrag = reinterpret_cast<const f16x8*>(wp);

    #pragma unroll 2
    for (int kf = 0; kf < KT; ++kf) {
      f16x8 a[FM];
      #pragma unroll
      for (int fm = 0; fm < FM; ++fm)
        a[fm] = wfrag[(size_t)(kf * MF + wm * FM + fm) * 64 + lane];
      f16x8 b[FB];
      #pragma unroll
      for (int fb = 0; fb < FB; ++fb)
        b[fb] = *reinterpret_cast<const f16x8*>(
                    act + swz((wb * FB + fb) * 32 + mlane, kf * 32 + h * 16));
      #pragma unroll
      for (int fm = 0; fm < FM; ++fm)
        #pragma unroll
        for (int fb = 0; fb < FB; ++fb)
          acc[fm][fb] = __builtin_amdgcn_mfma_f32_32x32x16_f16(a[fm], b[fb], acc[fm][fb], 0, 0, 0);
    }

    __syncthreads();   // everyone done reading act
    #pragma unroll
    for (int fm = 0; fm < FM; ++fm) {
      const int mbase = (wm * FM + fm) * 32;
      #pragma unroll
      for (int fb = 0; fb < FB; ++fb) {
        const int row = (wb * FB + fb) * 32 + mlane;   // batch row
        #pragma unroll
        for (int g = 0; g < 4; ++g) {
          const int m0 = mbase + g * 8 + 4 * h;        // 4 consecutive out-features
          f16x4 v;
          #pragma unroll
          for (int j = 0; j < 4; ++j)
            v[j] = (f16)fmaxf(acc[fm][fb][g * 4 + j], 0.0f);
          *reinterpret_cast<f16x4*>(act + swz(row, m0 * 2)) = v;
        }
      }
    }
  } else {
    __syncthreads();   // idle waves still rendezvous
  }
  __syncthreads();
}

__global__ __launch_bounds__(1024, 8)
void mlp_kernel(const float* __restrict__ x,
                const float* __restrict__ W1, const float* __restrict__ b1,
                const f16*   __restrict__ wpk,
                const float* __restrict__ b2, const float* __restrict__ b3,
                const float* __restrict__ b4, const float* __restrict__ b5,
                const float* __restrict__ b6, const float* __restrict__ b7,
                const float* __restrict__ b8, const float* __restrict__ b9,
                float* __restrict__ out) {
  __shared__ __align__(16) char act[MT * LDSP];   // 64 KiB -> 2 blocks/CU, 32 waves/CU
  const int row0 = blockIdx.x * MT;
  const int tid  = threadIdx.x;

  // ---- Layer 1: 2 -> 128, fp32 VALU; 8 features per thread, 64 rows ----
  {
    const int r  = tid >> 4;             // 0..63
    const int cb = (tid & 15) * 8;       // feature base, 8 cols/thread
    const float2 xv = reinterpret_cast<const float2*>(x)[row0 + r];
    f16x8 v;
    #pragma unroll
    for (int j = 0; j < 8; ++j) {
      int c = cb + j;
      v[j] = (f16)fmaxf(fmaf(xv.y, W1[128 + c], fmaf(xv.x, W1[c], b1[c])), 0.0f);
    }
    *reinterpret_cast<f16x8*>(act + swz(r, cb * 2)) = v;
  }
  __syncthreads();

  run_layer<8,  8,  8,  2>(act, wpk + OFF2, b2);  // 128 -> 256  FM=1 FB=1 (16 waves)
  run_layer<16, 16, 16, 1>(act, wpk + OFF3, b3);  // 256 -> 512  FM=1 FB=2
  // L4-L6 (512 -> 512): one emitted body, runtime rep loop (I-cache)
  for (int rep = 0; rep < 3; ++rep) {
    const float* bias = (rep == 0) ? b4 : (rep == 1) ? b5 : b6;
    run_layer<32, 16, 16, 1>(act, wpk + OFF4 + rep * (OFF5 - OFF4), bias);
  }
  run_layer<32, 8,  8,  2>(act, wpk + OFF7, b7);  // 512 -> 256  FM=1 FB=1 (16 waves)
  run_layer<16, 4,  4,  2>(act, wpk + OFF8, b8);  // 256 -> 128  FM=1 FB=1 (8 waves)

  // ---- Layer 9: 128 -> 3 (padded to 32), sigmoid; waves 0,1 = batch frags ----
  const int lane = tid & 63;
  const int wid  = tid >> 6;
  if (wid < 2) {
    const int mlane = lane & 31;
    const int h     = lane >> 5;
    f32x16 acc = (f32x16)0.0f;
    const f16x8* __restrict__ wfrag = reinterpret_cast<const f16x8*>(wpk + OFF9);
    #pragma unroll
    for (int kf = 0; kf < 8; ++kf) {
      f16x8 a = wfrag[(size_t)kf * 64 + lane];
      f16x8 b = *reinterpret_cast<const f16x8*>(
                    act + swz(wid * 32 + mlane, kf * 32 + h * 16));
      acc = __builtin_amdgcn_mfma_f32_32x32x16_f16(a, b, acc, 0, 0, 0);
    }
    if (h == 0) {   // regs 0..2 hold out-features 0..2 for these lanes
      const size_t orow = (size_t)(row0 + wid * 32 + mlane) * 3;
      #pragma unroll
      for (int r = 0; r < 3; ++r) {
        float v = acc[r] + b9[r];
        out[orow + r] = 1.0f / (1.0f + __expf(-v));
      }
    }
  }
}

extern "C" void kernel_launch(void* const* d_in, const int* in_sizes, int n_in,
                              void* d_out, int out_size, void* d_ws, size_t ws_size,
                              hipStream_t stream) {
  const float* x  = (const float*)d_in[0];
  const float* W1 = (const float*)d_in[1];  const float* b1 = (const float*)d_in[2];
  const float* W2 = (const float*)d_in[3];  const float* b2 = (const float*)d_in[4];
  const float* W3 = (const float*)d_in[5];  const float* b3 = (const float*)d_in[6];
  const float* W4 = (const float*)d_in[7];  const float* b4 = (const float*)d_in[8];
  const float* W5 = (const float*)d_in[9];  const float* b5 = (const float*)d_in[10];
  const float* W6 = (const float*)d_in[11]; const float* b6 = (const float*)d_in[12];
  const float* W7 = (const float*)d_in[13]; const float* b7 = (const float*)d_in[14];
  const float* W8 = (const float*)d_in[15]; const float* b8 = (const float*)d_in[16];
  const float* W9 = (const float*)d_in[17]; const float* b9 = (const float*)d_in[18];
  f16* wpk = (f16*)d_ws;

  repack_kernel<<<(TOTAL_FRAG_LANES + 255) / 256, 256, 0, stream>>>(
      W2, W3, W4, W5, W6, W7, W8, W9, wpk);

  mlp_kernel<<<1048576 / MT, 1024, 0, stream>>>(
      x, W1, b1, wpk, b2, b3, b4, b5, b6, b7, b8, b9, (float*)d_out);
}

// Round 9
// 2054.716 us; speedup vs baseline: 1.1612x; 1.1612x over previous
//
#include <hip/hip_runtime.h>

typedef _Float16 f16;
typedef __attribute__((ext_vector_type(4))) _Float16 f16x4;
typedef __attribute__((ext_vector_type(8))) _Float16 f16x8;
typedef __attribute__((ext_vector_type(16))) float f32x16;

#define MT 128           // batch rows per block
#define NBF 4            // batch fragments (MT/32)
#define LDSP 1024        // LDS row pitch bytes (512 f16 features)

// Packed-weight fragment offsets (f16 elements) inside d_ws
#define OFF2 0
#define OFF3 32768
#define OFF4 163840
#define OFF5 425984
#define OFF6 688128
#define OFF7 950272
#define OFF8 1081344
#define OFF9 1114112
#define TOTAL_FRAG_LANES 139776

// 32 rows -> 32 distinct 16B slots: conflict-free b128 column reads.
__device__ __forceinline__ uint32_t swz(int row, int colbytes) {
  return (uint32_t)(row * LDSP + (colbytes ^ ((row & 31) << 4)));
}

// weight repack: fp32 [K][N] -> fp16 A-fragment order.
// frag f = kf*MF + mf ; lane l holds m = mf*32 + (l&31), k = kf*16 + (l>>5)*8 + i
__global__ void repack_kernel(const float* __restrict__ W2, const float* __restrict__ W3,
                              const float* __restrict__ W4, const float* __restrict__ W5,
                              const float* __restrict__ W6, const float* __restrict__ W7,
                              const float* __restrict__ W8, const float* __restrict__ W9,
                              f16* __restrict__ ws) {
  int gid = blockIdx.x * 256 + threadIdx.x;
  if (gid >= TOTAL_FRAG_LANES) return;
  const float* src; int N, NT; size_t dst; int local;
  if      (gid <   4096) { src = W2; N = 256; NT = 8;  dst = OFF2; local = gid;          }
  else if (gid <  20480) { src = W3; N = 512; NT = 16; dst = OFF3; local = gid -   4096; }
  else if (gid <  53248) { src = W4; N = 512; NT = 16; dst = OFF4; local = gid -  20480; }
  else if (gid <  86016) { src = W5; N = 512; NT = 16; dst = OFF5; local = gid -  53248; }
  else if (gid < 118784) { src = W6; N = 512; NT = 16; dst = OFF6; local = gid -  86016; }
  else if (gid < 135168) { src = W7; N = 256; NT = 8;  dst = OFF7; local = gid - 118784; }
  else if (gid < 139264) { src = W8; N = 128; NT = 4;  dst = OFF8; local = gid - 135168; }
  else                   { src = W9; N = 3;   NT = 1;  dst = OFF9; local = gid - 139264; }
  int lane = local & 63;
  int frag = local >> 6;
  int kf = frag / NT, nf = frag % NT;
  int n  = nf * 32 + (lane & 31);
  int kb = kf * 16 + ((lane >> 5) << 3);
  f16x8 v;
  #pragma unroll
  for (int i = 0; i < 8; ++i) {
    float val = (n < N) ? src[(size_t)(kb + i) * N + n] : 0.0f;
    v[i] = (f16)val;
  }
  *reinterpret_cast<f16x8*>(ws + dst + (size_t)local * 8) = v;
}

// One layer: D = W_frag(A) x act(B).  act is [batch][feature] f16 in LDS.
// R4 geometry (FM=2, FB=4 on wide layers: both streams under pipe budget)
// + rolled pair-loop DOUBLE BUFFER of both weight (w0/w1, global) and
// activation (b0/b1, LDS) fragments: prefetch for kf+2 issues right after
// the even MFMA cluster, hiding L2/LDS latency under ~2 MFMA clusters of
// 2 interleaved waves.  Named buffers + unrolled fm/fb -> no dyn indexing.
template<int KT, int MF, int WMG, int WBG>
__device__ __forceinline__ void run_layer(char* act, const f16* __restrict__ wp,
                                          const float* __restrict__ bias) {
  constexpr int FM  = MF / WMG;    // out-feature frags per wave
  constexpr int FB  = NBF / WBG;   // batch frags per wave
  const int tid   = threadIdx.x;
  const int lane  = tid & 63;
  const int wid   = tid >> 6;
  const int wm    = wid / WBG;
  const int wb    = wid % WBG;
  const int mlane = lane & 31;
  const int h     = lane >> 5;

  f32x16 acc[FM][FB];
  #pragma unroll
  for (int fm = 0; fm < FM; ++fm) {
    const int mbase = (wm * FM + fm) * 32;
    #pragma unroll
    for (int g = 0; g < 4; ++g) {
      const float4 bb = *reinterpret_cast<const float4*>(&bias[mbase + g * 8 + 4 * h]);
      #pragma unroll
      for (int j = 0; j < 4; ++j)
        #pragma unroll
        for (int fb = 0; fb < FB; ++fb)
          acc[fm][fb][g * 4 + j] = ((const float*)&bb)[j];
    }
  }

  const f16x8* __restrict__ wfrag = reinterpret_cast<const f16x8*>(wp);
  #define WLOAD(d_, kf_) { _Pragma("unroll")                                   \
    for (int fm = 0; fm < FM; ++fm)                                            \
      d_[fm] = wfrag[(size_t)((kf_) * MF + wm * FM + fm) * 64 + lane]; }
  #define BLOAD(d_, kf_) { _Pragma("unroll")                                   \
    for (int fb = 0; fb < FB; ++fb)                                            \
      d_[fb] = *reinterpret_cast<const f16x8*>(                                \
                   act + swz((wb * FB + fb) * 32 + mlane, (kf_) * 32 + h * 16)); }
  #define MFMAS(w_, b_) { __builtin_amdgcn_s_setprio(1); _Pragma("unroll")     \
    for (int fm = 0; fm < FM; ++fm) { _Pragma("unroll")                        \
      for (int fb = 0; fb < FB; ++fb)                                          \
        acc[fm][fb] = __builtin_amdgcn_mfma_f32_32x32x16_f16(                  \
                          w_[fm], b_[fb], acc[fm][fb], 0, 0, 0); }             \
    __builtin_amdgcn_s_setprio(0); }

  f16x8 w0[FM], w1[FM], b0[FB], b1[FB];
  WLOAD(w0, 0); BLOAD(b0, 0);
  WLOAD(w1, 1); BLOAD(b1, 1);

  #pragma unroll 1
  for (int kf = 0; kf < KT; kf += 2) {
    // even body: consume (w0,b0)=kf, then prefetch kf+2 into them
    MFMAS(w0, b0);
    if (kf + 2 < KT) { WLOAD(w0, kf + 2); BLOAD(b0, kf + 2); }
    // odd body: consume (w1,b1)=kf+1, then prefetch kf+3
    MFMAS(w1, b1);
    if (kf + 3 < KT) { WLOAD(w1, kf + 3); BLOAD(b1, kf + 3); }
  }
  #undef WLOAD
  #undef BLOAD
  #undef MFMAS

  __syncthreads();   // everyone done reading act
  #pragma unroll
  for (int fm = 0; fm < FM; ++fm) {
    const int mbase = (wm * FM + fm) * 32;
    #pragma unroll
    for (int fb = 0; fb < FB; ++fb) {
      const int row = (wb * FB + fb) * 32 + mlane;   // batch row
      #pragma unroll
      for (int g = 0; g < 4; ++g) {
        const int m0 = mbase + g * 8 + 4 * h;        // 4 consecutive out-features
        f16x4 v;
        #pragma unroll
        for (int j = 0; j < 4; ++j)
          v[j] = (f16)fmaxf(acc[fm][fb][g * 4 + j], 0.0f);
        *reinterpret_cast<f16x4*>(act + swz(row, m0 * 2)) = v;
      }
    }
  }
  __syncthreads();
}

__global__ __launch_bounds__(512, 2)
void mlp_kernel(const float* __restrict__ x,
                const float* __restrict__ W1, const float* __restrict__ b1,
                const f16*   __restrict__ wpk,
                const float* __restrict__ b2, const float* __restrict__ b3,
                const float* __restrict__ b4, const float* __restrict__ b5,
                const float* __restrict__ b6, const float* __restrict__ b7,
                const float* __restrict__ b8, const float* __restrict__ b9,
                float* __restrict__ out) {
  __shared__ __align__(16) char act[MT * LDSP];   // 128 KiB, 1 block/CU
  const int row0 = blockIdx.x * MT;
  const int tid  = threadIdx.x;

  // ---- Layer 1: 2 -> 128, fp32 VALU; 32 features per thread, 128 rows ----
  {
    const int r  = tid >> 2;             // 0..127
    const int cb = (tid & 3) * 32;       // feature base, 32 cols/thread
    const float2 xv = reinterpret_cast<const float2*>(x)[row0 + r];
    #pragma unroll
    for (int q = 0; q < 4; ++q) {
      f16x8 v;
      #pragma unroll
      for (int j = 0; j < 8; ++j) {
        int c = cb + q * 8 + j;
        v[j] = (f16)fmaxf(fmaf(xv.y, W1[128 + c], fmaf(xv.x, W1[c], b1[c])), 0.0f);
      }
      *reinterpret_cast<f16x8*>(act + swz(r, cb * 2 + q * 16)) = v;
    }
  }
  __syncthreads();

  run_layer<8,  8,  8, 1>(act, wpk + OFF2, b2);   // 128 -> 256  FM=1 FB=4
  run_layer<16, 16, 8, 1>(act, wpk + OFF3, b3);   // 256 -> 512  FM=2 FB=4
  // L4-L6 (512 -> 512): one emitted body, runtime rep loop (I-cache)
  for (int rep = 0; rep < 3; ++rep) {
    const float* bias = (rep == 0) ? b4 : (rep == 1) ? b5 : b6;
    run_layer<32, 16, 8, 1>(act, wpk + OFF4 + rep * (OFF5 - OFF4), bias);
  }
  run_layer<32, 8,  8, 1>(act, wpk + OFF7, b7);   // 512 -> 256  FM=1 FB=4
  run_layer<16, 4,  4, 2>(act, wpk + OFF8, b8);   // 256 -> 128  FM=1 FB=2

  // ---- Layer 9: 128 -> 3 (padded to 32), sigmoid; waves 0..3 = batch frags ----
  const int lane = tid & 63;
  const int wid  = tid >> 6;
  if (wid < 4) {
    const int mlane = lane & 31;
    const int h     = lane >> 5;
    f32x16 acc = (f32x16)0.0f;
    const f16x8* __restrict__ wfrag = reinterpret_cast<const f16x8*>(wpk + OFF9);
    #pragma unroll
    for (int kf = 0; kf < 8; ++kf) {
      f16x8 a = wfrag[(size_t)kf * 64 + lane];
      f16x8 b = *reinterpret_cast<const f16x8*>(
                    act + swz(wid * 32 + mlane, kf * 32 + h * 16));
      acc = __builtin_amdgcn_mfma_f32_32x32x16_f16(a, b, acc, 0, 0, 0);
    }
    if (h == 0) {   // regs 0..2 hold out-features 0..2 for these lanes
      const size_t orow = (size_t)(row0 + wid * 32 + mlane) * 3;
      #pragma unroll
      for (int r = 0; r < 3; ++r) {
        float v = acc[r] + b9[r];
        out[orow + r] = 1.0f / (1.0f + __expf(-v));
      }
    }
  }
}

extern "C" void kernel_launch(void* const* d_in, const int* in_sizes, int n_in,
                              void* d_out, int out_size, void* d_ws, size_t ws_size,
                              hipStream_t stream) {
  const float* x  = (const float*)d_in[0];
  const float* W1 = (const float*)d_in[1];  const float* b1 = (const float*)d_in[2];
  const float* W2 = (const float*)d_in[3];  const float* b2 = (const float*)d_in[4];
  const float* W3 = (const float*)d_in[5];  const float* b3 = (const float*)d_in[6];
  const float* W4 = (const float*)d_in[7];  const float* b4 = (const float*)d_in[8];
  const float* W5 = (const float*)d_in[9];  const float* b5 = (const float*)d_in[10];
  const float* W6 = (const float*)d_in[11]; const float* b6 = (const float*)d_in[12];
  const float* W7 = (const float*)d_in[13]; const float* b7 = (const float*)d_in[14];
  const float* W8 = (const float*)d_in[15]; const float* b8 = (const float*)d_in[16];
  const float* W9 = (const float*)d_in[17]; const float* b9 = (const float*)d_in[18];
  f16* wpk = (f16*)d_ws;

  repack_kernel<<<(TOTAL_FRAG_LANES + 255) / 256, 256, 0, stream>>>(
      W2, W3, W4, W5, W6, W7, W8, W9, wpk);

  mlp_kernel<<<1048576 / MT, 512, 0, stream>>>(
      x, W1, b1, wpk, b2, b3, b4, b5, b6, b7, b8, b9, (float*)d_out);
}